// Round 1
// baseline (2494.003 us; speedup 1.0000x reference)
//
#include <hip/hip_runtime.h>
#include <hip/hip_bf16.h>

#define V_ 32000
#define D_ 256
#define H_ 512
#define B_ 32
#define T_ 64

typedef __attribute__((ext_vector_type(8))) __bf16 bf16x8;
typedef __attribute__((ext_vector_type(4))) float f32x4;

__device__ __forceinline__ void gld_lds16(const void* g, void* l) {
  __builtin_amdgcn_global_load_lds((const __attribute__((address_space(1))) void*)g,
                                   (__attribute__((address_space(3))) void*)l,
                                   16, 0, 0);
}

// ---------------- Wout [512][32000] f32 -> WoutT [32000][512] bf16 ----------------
__global__ __launch_bounds__(256) void k_transpose(const float* __restrict__ Wout,
                                                   __hip_bfloat16* __restrict__ WoutT) {
  __shared__ float tile[64][65];
  int v0 = blockIdx.x * 64;
  int h0 = blockIdx.y * 64;
  int tid = threadIdx.x;
#pragma unroll
  for (int i = 0; i < 16; ++i) {
    int idx = i * 256 + tid;
    int r = idx >> 6;   // h offset
    int c = idx & 63;   // v offset
    tile[r][c] = Wout[(size_t)(h0 + r) * V_ + v0 + c];
  }
  __syncthreads();
#pragma unroll
  for (int i = 0; i < 16; ++i) {
    int idx = i * 256 + tid;
    int rv = idx >> 6;  // v offset
    int ch = idx & 63;  // h offset
    WoutT[(size_t)(v0 + rv) * H_ + h0 + ch] = __float2bfloat16(tile[ch][rv]);
  }
}

// ---------------- x-projections: pre_g[n][1024], pre_c[n][512], n = b*T+t ----------
__global__ __launch_bounds__(256) void k_precompute(const int* __restrict__ widx,
                                                    const float* __restrict__ embW,
                                                    const float* __restrict__ Wg,
                                                    const float* __restrict__ bg,
                                                    const float* __restrict__ Wc,
                                                    const float* __restrict__ bc,
                                                    float* __restrict__ pre_g,
                                                    float* __restrict__ pre_c) {
  __shared__ __align__(16) float x2[D_][8];  // [d][token]
  __shared__ int wid[8];
  int tid = threadIdx.x;
  int n0 = blockIdx.x * 8;
  if (tid < 8) wid[tid] = widx[n0 + tid];  // widx flat [B][T], n = b*64+t
  __syncthreads();
#pragma unroll
  for (int i = 0; i < 8; ++i)
    x2[tid][i] = embW[(size_t)wid[i] * D_ + tid];
  __syncthreads();

  int J = blockIdx.y * 256 + tid;  // 0..1535 (uniform branch per block)
  float acc[8];
  if (J < 1024) {
    float bias = bg[J];
#pragma unroll
    for (int i = 0; i < 8; ++i) acc[i] = bias;
    for (int d = 0; d < D_; d += 4) {
      float4 xa0 = *(const float4*)&x2[d + 0][0];
      float4 xb0 = *(const float4*)&x2[d + 0][4];
      float4 xa1 = *(const float4*)&x2[d + 1][0];
      float4 xb1 = *(const float4*)&x2[d + 1][4];
      float4 xa2 = *(const float4*)&x2[d + 2][0];
      float4 xb2 = *(const float4*)&x2[d + 2][4];
      float4 xa3 = *(const float4*)&x2[d + 3][0];
      float4 xb3 = *(const float4*)&x2[d + 3][4];
      float w0 = Wg[(size_t)(d + 0) * 1024 + J];
      float w1 = Wg[(size_t)(d + 1) * 1024 + J];
      float w2 = Wg[(size_t)(d + 2) * 1024 + J];
      float w3 = Wg[(size_t)(d + 3) * 1024 + J];
      acc[0] = fmaf(xa0.x, w0, acc[0]); acc[1] = fmaf(xa0.y, w0, acc[1]);
      acc[2] = fmaf(xa0.z, w0, acc[2]); acc[3] = fmaf(xa0.w, w0, acc[3]);
      acc[4] = fmaf(xb0.x, w0, acc[4]); acc[5] = fmaf(xb0.y, w0, acc[5]);
      acc[6] = fmaf(xb0.z, w0, acc[6]); acc[7] = fmaf(xb0.w, w0, acc[7]);
      acc[0] = fmaf(xa1.x, w1, acc[0]); acc[1] = fmaf(xa1.y, w1, acc[1]);
      acc[2] = fmaf(xa1.z, w1, acc[2]); acc[3] = fmaf(xa1.w, w1, acc[3]);
      acc[4] = fmaf(xb1.x, w1, acc[4]); acc[5] = fmaf(xb1.y, w1, acc[5]);
      acc[6] = fmaf(xb1.z, w1, acc[6]); acc[7] = fmaf(xb1.w, w1, acc[7]);
      acc[0] = fmaf(xa2.x, w2, acc[0]); acc[1] = fmaf(xa2.y, w2, acc[1]);
      acc[2] = fmaf(xa2.z, w2, acc[2]); acc[3] = fmaf(xa2.w, w2, acc[3]);
      acc[4] = fmaf(xb2.x, w2, acc[4]); acc[5] = fmaf(xb2.y, w2, acc[5]);
      acc[6] = fmaf(xb2.z, w2, acc[6]); acc[7] = fmaf(xb2.w, w2, acc[7]);
      acc[0] = fmaf(xa3.x, w3, acc[0]); acc[1] = fmaf(xa3.y, w3, acc[1]);
      acc[2] = fmaf(xa3.z, w3, acc[2]); acc[3] = fmaf(xa3.w, w3, acc[3]);
      acc[4] = fmaf(xb3.x, w3, acc[4]); acc[5] = fmaf(xb3.y, w3, acc[5]);
      acc[6] = fmaf(xb3.z, w3, acc[6]); acc[7] = fmaf(xb3.w, w3, acc[7]);
    }
#pragma unroll
    for (int i = 0; i < 8; ++i)
      pre_g[(size_t)(n0 + i) * 1024 + J] = acc[i];
  } else {
    int Jc = J - 1024;
    float bias = bc[Jc];
#pragma unroll
    for (int i = 0; i < 8; ++i) acc[i] = bias;
    for (int d = 0; d < D_; ++d) {
      float4 xa = *(const float4*)&x2[d][0];
      float4 xb = *(const float4*)&x2[d][4];
      float w = Wc[(size_t)d * 512 + Jc];
      acc[0] = fmaf(xa.x, w, acc[0]); acc[1] = fmaf(xa.y, w, acc[1]);
      acc[2] = fmaf(xa.z, w, acc[2]); acc[3] = fmaf(xa.w, w, acc[3]);
      acc[4] = fmaf(xb.x, w, acc[4]); acc[5] = fmaf(xb.y, w, acc[5]);
      acc[6] = fmaf(xb.z, w, acc[6]); acc[7] = fmaf(xb.w, w, acc[7]);
    }
#pragma unroll
    for (int i = 0; i < 8; ++i)
      pre_c[(size_t)(n0 + i) * 512 + Jc] = acc[i];
  }
}

// ---------------- GRU: one block per batch element ----------------
__global__ __launch_bounds__(512) void k_gru(const int* __restrict__ num_words,
                                             const float* __restrict__ enc,
                                             const float* __restrict__ Wg,
                                             const float* __restrict__ Wc,
                                             const float* __restrict__ pre_g,
                                             const float* __restrict__ pre_c,
                                             __hip_bfloat16* __restrict__ A) {
  __shared__ __align__(16) float h[H_];
  __shared__ __align__(16) float rh[H_];
  __shared__ __align__(16) float u[H_];
  int b = blockIdx.x;
  int tid = threadIdx.x;
  h[tid] = enc[b * H_ + tid];
  int nw = num_words[b];
  const float* Wgh = Wg + 256 * 1024;  // rows 256..767
  const float* Wch = Wc + 256 * 512;

  for (int t = 0; t < T_; ++t) {
    __syncthreads();
    // ---- gates: this thread owns cols 2*tid, 2*tid+1 of the 1024 gate cols
    int c0 = 2 * tid;
    float2 pg = *(const float2*)&pre_g[(size_t)(b * T_ + t) * 1024 + c0];
    float a0 = pg.x, a1 = pg.y;
#pragma unroll 4
    for (int k = 0; k < H_; k += 4) {
      float4 hv = *(const float4*)&h[k];
      float2 w0 = *(const float2*)&Wgh[(size_t)(k + 0) * 1024 + c0];
      float2 w1 = *(const float2*)&Wgh[(size_t)(k + 1) * 1024 + c0];
      float2 w2 = *(const float2*)&Wgh[(size_t)(k + 2) * 1024 + c0];
      float2 w3 = *(const float2*)&Wgh[(size_t)(k + 3) * 1024 + c0];
      a0 = fmaf(hv.x, w0.x, a0); a1 = fmaf(hv.x, w0.y, a1);
      a0 = fmaf(hv.y, w1.x, a0); a1 = fmaf(hv.y, w1.y, a1);
      a0 = fmaf(hv.z, w2.x, a0); a1 = fmaf(hv.z, w2.y, a1);
      a0 = fmaf(hv.w, w3.x, a0); a1 = fmaf(hv.w, w3.y, a1);
    }
    float g0 = 1.0f / (1.0f + __expf(-a0));
    float g1 = 1.0f / (1.0f + __expf(-a1));
    if (c0 < H_) {           // r cols (tid < 256)
      rh[c0] = g0 * h[c0];
      rh[c0 + 1] = g1 * h[c0 + 1];
    } else {                 // u cols
      u[c0 - H_] = g0;
      u[c0 + 1 - H_] = g1;
    }
    __syncthreads();
    // ---- candidate + state update: this thread owns col tid (512 cols)
    float a2 = pre_c[(size_t)(b * T_ + t) * 512 + tid];
#pragma unroll 4
    for (int k = 0; k < H_; k += 4) {
      float4 rv = *(const float4*)&rh[k];
      float w0 = Wch[(size_t)(k + 0) * 512 + tid];
      float w1 = Wch[(size_t)(k + 1) * 512 + tid];
      float w2 = Wch[(size_t)(k + 2) * 512 + tid];
      float w3 = Wch[(size_t)(k + 3) * 512 + tid];
      a2 = fmaf(rv.x, w0, a2);
      a2 = fmaf(rv.y, w1, a2);
      a2 = fmaf(rv.z, w2, a2);
      a2 = fmaf(rv.w, w3, a2);
    }
    float c = tanhf(a2);
    float hv = h[tid], uu = u[tid];
    float hn = uu * hv + (1.0f - uu) * c;
    bool live = t < nw;
    A[(size_t)(b * T_ + t) * H_ + tid] = __float2bfloat16(live ? hn : 0.0f);
    if (live) h[tid] = hn;
  }
}

// ---------------- projection: C[2048][32000] = A[2048][512] @ WoutT^T + bout -------
__global__ __launch_bounds__(256) void k_proj(const __hip_bfloat16* __restrict__ Ap,
                                              const __hip_bfloat16* __restrict__ BTp,
                                              const float* __restrict__ bout,
                                              float* __restrict__ C) {
  __shared__ char As[128 * 64 * 2];
  __shared__ char Bs[128 * 64 * 2];
  int tid = threadIdx.x;
  int lane = tid & 63;
  int wave = tid >> 6;
  int m0 = blockIdx.x * 128;
  int n0 = blockIdx.y * 128;
  int wm = wave >> 1, wn = wave & 1;
  f32x4 acc[4][4] = {};

  const char* Ab = (const char*)Ap;
  const char* Bb = (const char*)BTp;

  for (int ks = 0; ks < 8; ++ks) {
    int k0 = ks * 64;
    __syncthreads();
#pragma unroll
    for (int inst = 0; inst < 4; ++inst) {
      int o = inst * 4096 + wave * 1024;        // wave-uniform LDS base
      int ol = o + lane * 16;                   // this lane's linear byte
      int r = ol >> 7;                          // tile row
      int cb = ol & 127;                        // col byte within row
      gld_lds16(Ab + ((size_t)(m0 + r) * 512 + k0) * 2 + cb, As + o);
      gld_lds16(Bb + ((size_t)(n0 + r) * 512 + k0) * 2 + cb, Bs + o);
    }
    __syncthreads();
#pragma unroll
    for (int kk = 0; kk < 64; kk += 32) {
      bf16x8 af[4], bfr[4];
      int cbyte = kk * 2 + ((lane >> 4) << 4);
#pragma unroll
      for (int mi = 0; mi < 4; ++mi) {
        int row = wm * 64 + mi * 16 + (lane & 15);
        af[mi] = *(const bf16x8*)(As + row * 128 + cbyte);
      }
#pragma unroll
      for (int ni = 0; ni < 4; ++ni) {
        int row = wn * 64 + ni * 16 + (lane & 15);
        bfr[ni] = *(const bf16x8*)(Bs + row * 128 + cbyte);
      }
#pragma unroll
      for (int mi = 0; mi < 4; ++mi)
#pragma unroll
        for (int ni = 0; ni < 4; ++ni)
          acc[mi][ni] = __builtin_amdgcn_mfma_f32_16x16x32_bf16(af[mi], bfr[ni], acc[mi][ni], 0, 0, 0);
    }
  }
  // epilogue: D[row=(lane>>4)*4+reg][col=lane&15] per 16x16 fragment
#pragma unroll
  for (int ni = 0; ni < 4; ++ni) {
    int col = n0 + wn * 64 + ni * 16 + (lane & 15);
    float bb = bout[col];
#pragma unroll
    for (int mi = 0; mi < 4; ++mi) {
      int rbase = m0 + wm * 64 + mi * 16 + ((lane >> 4) << 2);
#pragma unroll
      for (int rr = 0; rr < 4; ++rr) {
        C[(size_t)(rbase + rr) * V_ + col] = acc[mi][ni][rr] + bb;
      }
    }
  }
}

extern "C" void kernel_launch(void* const* d_in, const int* in_sizes, int n_in,
                              void* d_out, int out_size, void* d_ws, size_t ws_size,
                              hipStream_t stream) {
  const int* widx = (const int*)d_in[0];
  const int* num_words = (const int*)d_in[1];
  const float* enc = (const float*)d_in[2];
  const float* embW = (const float*)d_in[3];
  const float* Wg = (const float*)d_in[4];
  const float* bg = (const float*)d_in[5];
  const float* Wc = (const float*)d_in[6];
  const float* bc = (const float*)d_in[7];
  const float* Wout = (const float*)d_in[8];
  const float* bout = (const float*)d_in[9];
  float* out = (float*)d_out;

  char* ws = (char*)d_ws;
  float* pre_g = (float*)(ws);                              // 2048*1024*4 = 8,388,608
  float* pre_c = (float*)(ws + 8388608);                    // 2048*512*4  = 4,194,304
  __hip_bfloat16* A = (__hip_bfloat16*)(ws + 12582912);     // 2048*512*2  = 2,097,152
  __hip_bfloat16* WoutT = (__hip_bfloat16*)(ws + 14680064); // 32000*512*2 = 32,768,000

  hipLaunchKernelGGL(k_transpose, dim3(500, 8), dim3(256), 0, stream, Wout, WoutT);
  hipLaunchKernelGGL(k_precompute, dim3(256, 6), dim3(256), 0, stream,
                     widx, embW, Wg, bg, Wc, bc, pre_g, pre_c);
  hipLaunchKernelGGL(k_gru, dim3(32), dim3(512), 0, stream,
                     num_words, enc, Wg, Wc, pre_g, pre_c, A);
  hipLaunchKernelGGL(k_proj, dim3(16, 250), dim3(256), 0, stream, A, WoutT, bout, out);
}

// Round 2
// 2436.566 us; speedup vs baseline: 1.0236x; 1.0236x over previous
//
#include <hip/hip_runtime.h>
#include <hip/hip_bf16.h>

#define V_ 32000
#define D_ 256
#define H_ 512
#define B_ 32
#define T_ 64

typedef __attribute__((ext_vector_type(8))) __bf16 bf16x8;
typedef __attribute__((ext_vector_type(4))) float f32x4;
typedef _Float16 f16x2 __attribute__((ext_vector_type(2)));
typedef unsigned int u32t;

__device__ __forceinline__ u32t pack_h16(float a, float b) {
  union { _Float16 h; unsigned short u; } lo, hi;
  lo.h = (_Float16)a; hi.h = (_Float16)b;
  return (u32t)lo.u | ((u32t)hi.u << 16);
}

__device__ __forceinline__ float dot2(u32t w, u32t h, float acc) {
#if __has_builtin(__builtin_amdgcn_fdot2)
  return __builtin_amdgcn_fdot2(__builtin_bit_cast(f16x2, w),
                                __builtin_bit_cast(f16x2, h), acc, false);
#else
  f16x2 a = __builtin_bit_cast(f16x2, w);
  f16x2 b = __builtin_bit_cast(f16x2, h);
  return acc + (float)a.x * (float)b.x + (float)a.y * (float)b.y;
#endif
}

__device__ __forceinline__ void gld_lds16(const void* g, void* l) {
  __builtin_amdgcn_global_load_lds((const __attribute__((address_space(1))) void*)g,
                                   (__attribute__((address_space(3))) void*)l,
                                   16, 0, 0);
}

// ---------------- Wout [512][32000] f32 -> WoutT [32000][512] bf16 ----------------
__global__ __launch_bounds__(256) void k_transpose(const float* __restrict__ Wout,
                                                   __hip_bfloat16* __restrict__ WoutT) {
  __shared__ float tile[64][65];
  int v0 = blockIdx.x * 64;
  int h0 = blockIdx.y * 64;
  int tid = threadIdx.x;
#pragma unroll
  for (int i = 0; i < 16; ++i) {
    int idx = i * 256 + tid;
    int r = idx >> 6;
    int c = idx & 63;
    tile[r][c] = Wout[(size_t)(h0 + r) * V_ + v0 + c];
  }
  __syncthreads();
#pragma unroll
  for (int i = 0; i < 16; ++i) {
    int idx = i * 256 + tid;
    int rv = idx >> 6;
    int ch = idx & 63;
    WoutT[(size_t)(v0 + rv) * H_ + h0 + ch] = __float2bfloat16(tile[ch][rv]);
  }
}

// ---------------- weight repack: f32 [k][j] -> packed f16x2 per-column ----------------
__global__ __launch_bounds__(256) void k_repack_g(const float* __restrict__ Wg,
                                                  u32t* __restrict__ Wgt) {
  int i = blockIdx.x;  // 0..255 (k-pair)
  const float* r0 = Wg + (size_t)(256 + 2 * i) * 1024;
  const float* r1 = r0 + 1024;
  for (int j = threadIdx.x; j < 1024; j += 256)
    Wgt[(size_t)j * 256 + i] = pack_h16(r0[j], r1[j]);
}
__global__ __launch_bounds__(256) void k_repack_c(const float* __restrict__ Wc,
                                                  u32t* __restrict__ Wct) {
  int i = blockIdx.x;  // 0..127
#pragma unroll
  for (int half = 0; half < 2; ++half) {
    const float* r0 = Wc + (size_t)(256 + half * 256 + 2 * i) * 512;
    const float* r1 = r0 + 512;
    for (int j = threadIdx.x; j < 512; j += 256)
      Wct[(size_t)j * 256 + half * 128 + i] = pack_h16(r0[j], r1[j]);
  }
}

// ---------------- x-projection (gate): pre_g[n][1024] = x_n @ Wg[:256] + bg ----------
__global__ __launch_bounds__(256) void k_precompute_g(const int* __restrict__ widx,
                                                      const float* __restrict__ embW,
                                                      const float* __restrict__ Wg,
                                                      const float* __restrict__ bg,
                                                      float* __restrict__ pre_g) {
  __shared__ __align__(16) float x2[D_][8];
  __shared__ int wid[8];
  int tid = threadIdx.x;
  int n0 = blockIdx.x * 8;
  if (tid < 8) wid[tid] = widx[n0 + tid];
  __syncthreads();
#pragma unroll
  for (int i = 0; i < 8; ++i)
    x2[tid][i] = embW[(size_t)wid[i] * D_ + tid];
  __syncthreads();

  int J = blockIdx.y * 256 + tid;  // 0..1023
  float bias = bg[J];
  float acc[8];
#pragma unroll
  for (int i = 0; i < 8; ++i) acc[i] = bias;
  for (int d = 0; d < D_; ++d) {
    float4 xa = *(const float4*)&x2[d][0];
    float4 xb = *(const float4*)&x2[d][4];
    float w = Wg[(size_t)d * 1024 + J];
    acc[0] = fmaf(xa.x, w, acc[0]); acc[1] = fmaf(xa.y, w, acc[1]);
    acc[2] = fmaf(xa.z, w, acc[2]); acc[3] = fmaf(xa.w, w, acc[3]);
    acc[4] = fmaf(xb.x, w, acc[4]); acc[5] = fmaf(xb.y, w, acc[5]);
    acc[6] = fmaf(xb.z, w, acc[6]); acc[7] = fmaf(xb.w, w, acc[7]);
  }
#pragma unroll
  for (int i = 0; i < 8; ++i)
    pre_g[(size_t)(n0 + i) * 1024 + J] = acc[i];
}

// ---------------- x-projection (cand): pre_c[n][512] = x_n @ Wc[:256] + bc ----------
__global__ __launch_bounds__(256) void k_precompute_c(const int* __restrict__ widx,
                                                      const float* __restrict__ embW,
                                                      const float* __restrict__ Wc,
                                                      const float* __restrict__ bc,
                                                      float* __restrict__ pre_c) {
  __shared__ __align__(16) float x2[D_][8];
  __shared__ int wid[8];
  int tid = threadIdx.x;
  int n0 = blockIdx.x * 8;
  if (tid < 8) wid[tid] = widx[n0 + tid];
  __syncthreads();
#pragma unroll
  for (int i = 0; i < 8; ++i)
    x2[tid][i] = embW[(size_t)wid[i] * D_ + tid];
  __syncthreads();

  int Jc = blockIdx.y * 256 + tid;  // 0..511
  float bias = bc[Jc];
  float acc[8];
#pragma unroll
  for (int i = 0; i < 8; ++i) acc[i] = bias;
  for (int d = 0; d < D_; ++d) {
    float4 xa = *(const float4*)&x2[d][0];
    float4 xb = *(const float4*)&x2[d][4];
    float w = Wc[(size_t)d * 512 + Jc];
    acc[0] = fmaf(xa.x, w, acc[0]); acc[1] = fmaf(xa.y, w, acc[1]);
    acc[2] = fmaf(xa.z, w, acc[2]); acc[3] = fmaf(xa.w, w, acc[3]);
    acc[4] = fmaf(xb.x, w, acc[4]); acc[5] = fmaf(xb.y, w, acc[5]);
    acc[6] = fmaf(xb.z, w, acc[6]); acc[7] = fmaf(xb.w, w, acc[7]);
  }
#pragma unroll
  for (int i = 0; i < 8; ++i)
    pre_c[(size_t)(n0 + i) * 512 + Jc] = acc[i];
}

// ---------------- GRU v2: weights register-resident, one block (1024 thr) per batch ----
__global__ __launch_bounds__(1024, 4) void k_gru2(const int* __restrict__ num_words,
                                                  const float* __restrict__ enc,
                                                  const u32t* __restrict__ Wgt,
                                                  const u32t* __restrict__ Wct,
                                                  const float* __restrict__ pre_g,
                                                  const float* __restrict__ pre_c,
                                                  __hip_bfloat16* __restrict__ A) {
  __shared__ __align__(16) float h32[H_];
  __shared__ __align__(16) float u32s[H_];
  __shared__ __align__(16) u32t h2[H_ / 2];
  __shared__ __align__(16) u32t rh2[H_ / 2];
  int b = blockIdx.x;
  int tid = threadIdx.x;
  int nw = num_words[b];

  uint4 wg4[64];
  const uint4* wgp = (const uint4*)(Wgt + (size_t)tid * 256);
#pragma unroll
  for (int i = 0; i < 64; ++i) wg4[i] = wgp[i];
  uint4 wc4[32];
  const uint4* wcp = (const uint4*)(Wct + (size_t)(tid >> 1) * 256 + (size_t)(tid & 1) * 128);
#pragma unroll
  for (int i = 0; i < 32; ++i) wc4[i] = wcp[i];

  if (tid < H_) h32[tid] = enc[b * H_ + tid];
  if (tid < H_ / 2) h2[tid] = pack_h16(enc[b * H_ + 2 * tid], enc[b * H_ + 2 * tid + 1]);
  __syncthreads();

  for (int t = 0; t < T_; ++t) {
    float pg = pre_g[(size_t)(b * T_ + t) * 1024 + tid];
    float a0 = 0.f, a1 = 0.f, a2 = 0.f, a3 = 0.f;
    const uint4* hv4 = (const uint4*)h2;
#pragma unroll
    for (int i = 0; i < 64; ++i) {
      uint4 hv = hv4[i];
      a0 = dot2(wg4[i].x, hv.x, a0);
      a1 = dot2(wg4[i].y, hv.y, a1);
      a2 = dot2(wg4[i].z, hv.z, a2);
      a3 = dot2(wg4[i].w, hv.w, a3);
    }
    float g = 1.f / (1.f + __expf(-((a0 + a1) + (a2 + a3) + pg)));
    if (tid < H_) {
      float rh = g * h32[tid];
      u32t rf = pack_h16(rh, 0.f) & 0xffffu;
      u32t other = (u32t)__shfl_xor((int)rf, 1);
      if ((tid & 1) == 0) rh2[tid >> 1] = rf | (other << 16);
    } else {
      u32s[tid - H_] = g;
    }
    __syncthreads();

    int j = tid >> 1, half = tid & 1;
    float c0 = 0.f, c1 = 0.f, c2 = 0.f, c3 = 0.f;
    const uint4* rv4 = (const uint4*)rh2 + half * 32;
#pragma unroll
    for (int i = 0; i < 32; ++i) {
      uint4 rv = rv4[i];
      c0 = dot2(wc4[i].x, rv.x, c0);
      c1 = dot2(wc4[i].y, rv.y, c1);
      c2 = dot2(wc4[i].z, rv.z, c2);
      c3 = dot2(wc4[i].w, rv.w, c3);
    }
    float cacc = (c0 + c1) + (c2 + c3);
    if (half == 0) cacc += pre_c[(size_t)(b * T_ + t) * 512 + j];
    cacc += __shfl_xor(cacc, 1);
    float c = tanhf(cacc);
    float u = u32s[j];
    float hold = h32[j];
    float hn = u * hold + (1.f - u) * c;
    bool live = t < nw;
    float hnext = live ? hn : hold;
    u32t hf = pack_h16(hnext, 0.f) & 0xffffu;
    u32t hother = (u32t)__shfl_xor((int)hf, 2);
    if ((tid & 1) == 0) {
      A[(size_t)(b * T_ + t) * H_ + j] = __float2bfloat16(live ? hn : 0.f);
      h32[j] = hnext;
      if ((tid & 3) == 0) h2[j >> 1] = hf | (hother << 16);
    }
    __syncthreads();
  }
}

// ---------------- projection: C[2048][32000] = A[2048][512] @ WoutT^T + bout -------
__global__ __launch_bounds__(256) void k_proj(const __hip_bfloat16* __restrict__ Ap,
                                              const __hip_bfloat16* __restrict__ BTp,
                                              const float* __restrict__ bout,
                                              float* __restrict__ C) {
  __shared__ char As[128 * 64 * 2];
  __shared__ char Bs[128 * 64 * 2];
  int tid = threadIdx.x;
  int lane = tid & 63;
  int wave = tid >> 6;
  int m0 = blockIdx.x * 128;
  int n0 = blockIdx.y * 128;
  int wm = wave >> 1, wn = wave & 1;
  f32x4 acc[4][4] = {};

  const char* Ab = (const char*)Ap;
  const char* Bb = (const char*)BTp;

  for (int ks = 0; ks < 8; ++ks) {
    int k0 = ks * 64;
    __syncthreads();
#pragma unroll
    for (int inst = 0; inst < 4; ++inst) {
      int o = inst * 4096 + wave * 1024;
      int ol = o + lane * 16;
      int r = ol >> 7;
      int cb = ol & 127;
      gld_lds16(Ab + ((size_t)(m0 + r) * 512 + k0) * 2 + cb, As + o);
      gld_lds16(Bb + ((size_t)(n0 + r) * 512 + k0) * 2 + cb, Bs + o);
    }
    __syncthreads();
#pragma unroll
    for (int kk = 0; kk < 64; kk += 32) {
      bf16x8 af[4], bfr[4];
      int cbyte = kk * 2 + ((lane >> 4) << 4);
#pragma unroll
      for (int mi = 0; mi < 4; ++mi) {
        int row = wm * 64 + mi * 16 + (lane & 15);
        af[mi] = *(const bf16x8*)(As + row * 128 + cbyte);
      }
#pragma unroll
      for (int ni = 0; ni < 4; ++ni) {
        int row = wn * 64 + ni * 16 + (lane & 15);
        bfr[ni] = *(const bf16x8*)(Bs + row * 128 + cbyte);
      }
#pragma unroll
      for (int mi = 0; mi < 4; ++mi)
#pragma unroll
        for (int ni = 0; ni < 4; ++ni)
          acc[mi][ni] = __builtin_amdgcn_mfma_f32_16x16x32_bf16(af[mi], bfr[ni], acc[mi][ni], 0, 0, 0);
    }
  }
#pragma unroll
  for (int ni = 0; ni < 4; ++ni) {
    int col = n0 + wn * 64 + ni * 16 + (lane & 15);
    float bb = bout[col];
#pragma unroll
    for (int mi = 0; mi < 4; ++mi) {
      int rbase = m0 + wm * 64 + mi * 16 + ((lane >> 4) << 2);
#pragma unroll
      for (int rr = 0; rr < 4; ++rr) {
        C[(size_t)(rbase + rr) * V_ + col] = acc[mi][ni][rr] + bb;
      }
    }
  }
}

extern "C" void kernel_launch(void* const* d_in, const int* in_sizes, int n_in,
                              void* d_out, int out_size, void* d_ws, size_t ws_size,
                              hipStream_t stream) {
  const int* widx = (const int*)d_in[0];
  const int* num_words = (const int*)d_in[1];
  const float* enc = (const float*)d_in[2];
  const float* embW = (const float*)d_in[3];
  const float* Wg = (const float*)d_in[4];
  const float* bg = (const float*)d_in[5];
  const float* Wc = (const float*)d_in[6];
  const float* bc = (const float*)d_in[7];
  const float* Wout = (const float*)d_in[8];
  const float* bout = (const float*)d_in[9];
  float* out = (float*)d_out;

  char* ws = (char*)d_ws;
  float* pre_g = (float*)(ws);                              // 8,388,608
  float* pre_c = (float*)(ws + 8388608);                    // 4,194,304
  __hip_bfloat16* A = (__hip_bfloat16*)(ws + 12582912);     // 2,097,152
  __hip_bfloat16* WoutT = (__hip_bfloat16*)(ws + 14680064); // 32,768,000
  u32t* Wgt = (u32t*)(ws + 47448064);                       // 1,048,576
  u32t* Wct = (u32t*)(ws + 48496640);                       //   524,288

  hipLaunchKernelGGL(k_repack_g, dim3(256), dim3(256), 0, stream, Wg, Wgt);
  hipLaunchKernelGGL(k_repack_c, dim3(128), dim3(256), 0, stream, Wc, Wct);
  hipLaunchKernelGGL(k_transpose, dim3(500, 8), dim3(256), 0, stream, Wout, WoutT);
  hipLaunchKernelGGL(k_precompute_g, dim3(256, 4), dim3(256), 0, stream,
                     widx, embW, Wg, bg, pre_g);
  hipLaunchKernelGGL(k_precompute_c, dim3(256, 2), dim3(256), 0, stream,
                     widx, embW, Wc, bc, pre_c);
  hipLaunchKernelGGL(k_gru2, dim3(32), dim3(1024), 0, stream,
                     num_words, enc, Wgt, Wct, pre_g, pre_c, A);
  hipLaunchKernelGGL(k_proj, dim3(16, 250), dim3(256), 0, stream, A, WoutT, bout, out);
}

// Round 3
// 1678.819 us; speedup vs baseline: 1.4856x; 1.4514x over previous
//
#include <hip/hip_runtime.h>
#include <hip/hip_bf16.h>

#define V_ 32000
#define D_ 256
#define H_ 512
#define B_ 32
#define T_ 64
#define G_ 64   // blocks in the persistent GRU kernel

typedef __attribute__((ext_vector_type(8))) __bf16 bf16x8;
typedef __attribute__((ext_vector_type(4))) float f32x4;
typedef _Float16 f16x2 __attribute__((ext_vector_type(2)));
typedef unsigned int u32t;
typedef unsigned long long u64t;

__device__ __forceinline__ u32t pack_h16(float a, float b) {
  union { _Float16 h; unsigned short u; } lo, hi;
  lo.h = (_Float16)a; hi.h = (_Float16)b;
  return (u32t)lo.u | ((u32t)hi.u << 16);
}

__device__ __forceinline__ float dot2(u32t w, u32t h, float acc) {
#if __has_builtin(__builtin_amdgcn_fdot2)
  return __builtin_amdgcn_fdot2(__builtin_bit_cast(f16x2, w),
                                __builtin_bit_cast(f16x2, h), acc, false);
#else
  f16x2 a = __builtin_bit_cast(f16x2, w);
  f16x2 b = __builtin_bit_cast(f16x2, h);
  return acc + (float)a.x * (float)b.x + (float)a.y * (float)b.y;
#endif
}

__device__ __forceinline__ void gld_lds16(const void* g, void* l) {
  __builtin_amdgcn_global_load_lds((const __attribute__((address_space(1))) void*)g,
                                   (__attribute__((address_space(3))) void*)l,
                                   16, 0, 0);
}

// ---------------- Wout [512][32000] f32 -> WoutT [32000][512] bf16 ----------------
__global__ __launch_bounds__(256) void k_transpose(const float* __restrict__ Wout,
                                                   __hip_bfloat16* __restrict__ WoutT) {
  __shared__ float tile[64][65];
  int v0 = blockIdx.x * 64;
  int h0 = blockIdx.y * 64;
  int tid = threadIdx.x;
#pragma unroll
  for (int i = 0; i < 16; ++i) {
    int idx = i * 256 + tid;
    int r = idx >> 6;
    int c = idx & 63;
    tile[r][c] = Wout[(size_t)(h0 + r) * V_ + v0 + c];
  }
  __syncthreads();
#pragma unroll
  for (int i = 0; i < 16; ++i) {
    int idx = i * 256 + tid;
    int rv = idx >> 6;
    int ch = idx & 63;
    WoutT[(size_t)(v0 + rv) * H_ + h0 + ch] = __float2bfloat16(tile[ch][rv]);
  }
}

// ---------------- GRU weight packs (f16 pairs, block-sliced layouts) ----------------
// Wg1: for block g<64: [i4 0..63][c 0..15] uint4 ; uint4 = halfs k=i4*8..+7 of gate col j=g*16+c
__global__ __launch_bounds__(256) void k_pack_g1(const float* __restrict__ Wg,
                                                 u32t* __restrict__ Wg1) {
  int j = blockIdx.x;            // 0..1023
  int g = j >> 4, c = j & 15;
  int ku = threadIdx.x;          // k-pair 0..255
  int k = 2 * ku;
  u32t val = pack_h16(Wg[(size_t)(256 + k) * 1024 + j], Wg[(size_t)(257 + k) * 1024 + j]);
  int i4 = ku >> 2, s = ku & 3;
  Wg1[(((size_t)g * 64 + i4) * 16 + c) * 4 + s] = val;
}
// Wc1: for block g<64: [i4 0..63][c2 0..7] uint4 ; col jc=g*8+c2
__global__ __launch_bounds__(256) void k_pack_c1(const float* __restrict__ Wc,
                                                 u32t* __restrict__ Wc1) {
  int jc = blockIdx.x;           // 0..511
  int g = jc >> 3, c2 = jc & 7;
  int ku = threadIdx.x;
  int k = 2 * ku;
  u32t val = pack_h16(Wc[(size_t)(256 + k) * 512 + jc], Wc[(size_t)(257 + k) * 512 + jc]);
  int i4 = ku >> 2, s = ku & 3;
  Wc1[(((size_t)g * 64 + i4) * 8 + c2) * 4 + s] = val;
}

// ---------------- x-projection (gate): pre_g[n][1024] = x_n @ Wg[:256] + bg ----------
__global__ __launch_bounds__(256) void k_precompute_g(const int* __restrict__ widx,
                                                      const float* __restrict__ embW,
                                                      const float* __restrict__ Wg,
                                                      const float* __restrict__ bg,
                                                      float* __restrict__ pre_g) {
  __shared__ __align__(16) float x2[D_][8];
  __shared__ int wid[8];
  int tid = threadIdx.x;
  int n0 = blockIdx.x * 8;
  if (tid < 8) wid[tid] = widx[n0 + tid];
  __syncthreads();
#pragma unroll
  for (int i = 0; i < 8; ++i)
    x2[tid][i] = embW[(size_t)wid[i] * D_ + tid];
  __syncthreads();

  int J = blockIdx.y * 256 + tid;  // 0..1023
  float bias = bg[J];
  float acc[8];
#pragma unroll
  for (int i = 0; i < 8; ++i) acc[i] = bias;
  for (int d = 0; d < D_; ++d) {
    float4 xa = *(const float4*)&x2[d][0];
    float4 xb = *(const float4*)&x2[d][4];
    float w = Wg[(size_t)d * 1024 + J];
    acc[0] = fmaf(xa.x, w, acc[0]); acc[1] = fmaf(xa.y, w, acc[1]);
    acc[2] = fmaf(xa.z, w, acc[2]); acc[3] = fmaf(xa.w, w, acc[3]);
    acc[4] = fmaf(xb.x, w, acc[4]); acc[5] = fmaf(xb.y, w, acc[5]);
    acc[6] = fmaf(xb.z, w, acc[6]); acc[7] = fmaf(xb.w, w, acc[7]);
  }
#pragma unroll
  for (int i = 0; i < 8; ++i)
    pre_g[(size_t)(n0 + i) * 1024 + J] = acc[i];
}

// ---------------- x-projection (cand): pre_c[n][512] = x_n @ Wc[:256] + bc ----------
__global__ __launch_bounds__(256) void k_precompute_c(const int* __restrict__ widx,
                                                      const float* __restrict__ embW,
                                                      const float* __restrict__ Wc,
                                                      const float* __restrict__ bc,
                                                      float* __restrict__ pre_c) {
  __shared__ __align__(16) float x2[D_][8];
  __shared__ int wid[8];
  int tid = threadIdx.x;
  int n0 = blockIdx.x * 8;
  if (tid < 8) wid[tid] = widx[n0 + tid];
  __syncthreads();
#pragma unroll
  for (int i = 0; i < 8; ++i)
    x2[tid][i] = embW[(size_t)wid[i] * D_ + tid];
  __syncthreads();

  int Jc = blockIdx.y * 256 + tid;  // 0..511
  float bias = bc[Jc];
  float acc[8];
#pragma unroll
  for (int i = 0; i < 8; ++i) acc[i] = bias;
  for (int d = 0; d < D_; ++d) {
    float4 xa = *(const float4*)&x2[d][0];
    float4 xb = *(const float4*)&x2[d][4];
    float w = Wc[(size_t)d * 512 + Jc];
    acc[0] = fmaf(xa.x, w, acc[0]); acc[1] = fmaf(xa.y, w, acc[1]);
    acc[2] = fmaf(xa.z, w, acc[2]); acc[3] = fmaf(xa.w, w, acc[3]);
    acc[4] = fmaf(xb.x, w, acc[4]); acc[5] = fmaf(xb.y, w, acc[5]);
    acc[6] = fmaf(xb.z, w, acc[6]); acc[7] = fmaf(xb.w, w, acc[7]);
  }
#pragma unroll
  for (int i = 0; i < 8; ++i)
    pre_c[(size_t)(n0 + i) * 512 + Jc] = acc[i];
}

// ---------------- GRU init: pack enc -> HG (f16 pairs, word = wk*32+b), zero barriers ----
__global__ __launch_bounds__(256) void k_gru_init(const float* __restrict__ enc,
                                                  u32t* __restrict__ HG,
                                                  int* __restrict__ bar) {
  int tid = blockIdx.x * 256 + threadIdx.x;  // 0..8191
  int wk = tid >> 5, b = tid & 31;
  u32t v = pack_h16(enc[b * H_ + 2 * wk], enc[b * H_ + 2 * wk + 1]);
  __hip_atomic_store(&HG[tid], v, __ATOMIC_RELAXED, __HIP_MEMORY_SCOPE_AGENT);
  if (blockIdx.x == 0 && threadIdx.x < 256)
    __hip_atomic_store(&bar[threadIdx.x], 0, __ATOMIC_RELAXED, __HIP_MEMORY_SCOPE_AGENT);
}

// grid barrier: counter-per-instance, agent scope
__device__ __forceinline__ void grid_barrier(int* bar, int idx) {
  __syncthreads();
  if (threadIdx.x == 0) {
    int prev = __hip_atomic_fetch_add(&bar[idx], 1, __ATOMIC_ACQ_REL, __HIP_MEMORY_SCOPE_AGENT);
    if (prev + 1 < G_) {
      while (__hip_atomic_load(&bar[idx], __ATOMIC_ACQUIRE, __HIP_MEMORY_SCOPE_AGENT) < G_) {
        __builtin_amdgcn_s_sleep(2);
      }
    }
  }
  __syncthreads();
}

// stage a 32KB (8192-word) global buffer (word = wk*32+b) into LDS [i4][b] uint4 tiles
__device__ __forceinline__ void stage32k(const u64t* __restrict__ src,
                                         uint4 (*lds4)[32], int tid) {
#pragma unroll
  for (int rep = 0; rep < 8; ++rep) {
    int q = rep * 512 + tid;       // u64 chunk: words 2q, 2q+1
    u64t v = __hip_atomic_load(&src[q], __ATOMIC_RELAXED, __HIP_MEMORY_SCOPE_AGENT);
    int word = q * 2;
    int wk = word >> 5, b = word & 31;
    int i4 = wk >> 2, sub = wk & 3;
    u32t* dst = (u32t*)&lds4[i4][0];
    dst[(b + 0) * 4 + sub] = (u32t)v;
    dst[(b + 1) * 4 + sub] = (u32t)(v >> 32);
  }
}

// ---------------- GRU v3: column-parallel persistent kernel, 64 blocks ----------------
// phase1: block g owns gate cols [g*16, g*16+16) for all 32 batches (g<32 -> r, else u)
// phase2: block g owns cand cols [g*8, g*8+8) for all 32 batches (2-way K-split + shfl)
__global__ __launch_bounds__(512) void k_gru3(const int* __restrict__ num_words,
                                              const u32t* __restrict__ Wg1,
                                              const u32t* __restrict__ Wc1,
                                              const float* __restrict__ pre_g,
                                              const float* __restrict__ pre_c,
                                              u32t* __restrict__ RHg,
                                              u32t* __restrict__ HG,
                                              u32t* __restrict__ U,
                                              int* __restrict__ bar,
                                              u32t* __restrict__ A32) {
  __shared__ uint4 h4[64][32];
  __shared__ uint4 rh4[64][32];
  int g = blockIdx.x;
  int tid = threadIdx.x;
  int lane = tid & 63;
  int w = tid >> 6;  // wave 0..7
  // phase1 lane mapping: 16 cols x 4 batches per wave
  int c = lane & 15;
  int b1 = w * 4 + (lane >> 4);
  int j1 = g * 16 + c;
  bool is_r = g < 32;
  // phase2 lane mapping: 8 cols x 4 batches x 2 k-halves per wave
  int c2 = lane & 7;
  int b2 = w * 4 + ((lane >> 3) & 3);
  int kh = lane >> 5;
  int jc = g * 8 + c2;
  int nw2 = num_words[b2];
  const uint4* Wg1v = (const uint4*)Wg1 + (size_t)g * 1024;  // [i4][c]
  const uint4* Wc1v = (const uint4*)Wc1 + (size_t)g * 512;   // [i4g][c2]

  for (int t = 0; t < T_; ++t) {
    // ---- stage h (HG -> h4) ----
    stage32k((const u64t*)HG, h4, tid);
    __syncthreads();

    // ---- phase 1: gate col j1, batch b1 ----
    float acc = pre_g[(size_t)(b1 * T_ + t) * 1024 + j1];
#pragma unroll 16
    for (int i4 = 0; i4 < 64; ++i4) {
      uint4 wv = Wg1v[i4 * 16 + c];
      uint4 hv = h4[i4][b1];
      acc = dot2(wv.x, hv.x, acc);
      acc = dot2(wv.y, hv.y, acc);
      acc = dot2(wv.z, hv.z, acc);
      acc = dot2(wv.w, hv.w, acc);
    }
    float gate = 1.f / (1.f + __expf(-acc));
    if (is_r) {
      // rh = r * h ; pack pairs (even c holds low, odd c high) -> one u32 store
      u32t hw = ((const u32t*)&h4[j1 >> 3][b1])[(j1 >> 1) & 3];
      f16x2 hp = __builtin_bit_cast(f16x2, hw);
      float hh = (j1 & 1) ? (float)hp.y : (float)hp.x;
      u32t mine = pack_h16(gate * hh, 0.f) & 0xffffu;
      u32t oth = (u32t)__shfl_xor((int)mine, 1);
      if ((c & 1) == 0)
        __hip_atomic_store(&RHg[(j1 >> 1) * 32 + b1], mine | (oth << 16),
                           __ATOMIC_RELAXED, __HIP_MEMORY_SCOPE_AGENT);
    } else {
      __hip_atomic_store(&U[(size_t)b1 * H_ + (j1 - H_)], __builtin_bit_cast(u32t, gate),
                         __ATOMIC_RELAXED, __HIP_MEMORY_SCOPE_AGENT);
    }
    grid_barrier(bar, t * 2);

    // ---- stage rh (RHg -> rh4) ----
    stage32k((const u64t*)RHg, rh4, tid);
    __syncthreads();

    // ---- phase 2: cand col jc, batch b2, k-half kh ----
    float cacc = 0.f;
#pragma unroll 16
    for (int i = 0; i < 32; ++i) {
      int i4 = kh * 32 + i;
      uint4 wv = Wc1v[i4 * 8 + c2];
      uint4 rv = rh4[i4][b2];
      cacc = dot2(wv.x, rv.x, cacc);
      cacc = dot2(wv.y, rv.y, cacc);
      cacc = dot2(wv.z, rv.z, cacc);
      cacc = dot2(wv.w, rv.w, cacc);
    }
    cacc += __shfl_xor(cacc, 32);
    cacc += pre_c[(size_t)(b2 * T_ + t) * 512 + jc];
    float cv = tanhf(cacc);
    u32t uw = __hip_atomic_load(&U[(size_t)b2 * H_ + jc], __ATOMIC_RELAXED,
                                __HIP_MEMORY_SCOPE_AGENT);
    float uu = __builtin_bit_cast(float, uw);
    u32t hw = ((const u32t*)&h4[jc >> 3][b2])[(jc >> 1) & 3];
    f16x2 hp = __builtin_bit_cast(f16x2, hw);
    float hold = (jc & 1) ? (float)hp.y : (float)hp.x;
    float hn = uu * hold + (1.f - uu) * cv;
    bool live = t < nw2;
    float hnext = live ? hn : hold;
    // pack pair stores (even c2 lane writes the u32)
    u32t mh = pack_h16(hnext, 0.f) & 0xffffu;
    u32t ma = (u32t)__hip_bfloat16_raw(__float2bfloat16(live ? hn : 0.f)).x;
    u32t oh = (u32t)__shfl_xor((int)mh, 1);
    u32t oa = (u32t)__shfl_xor((int)ma, 1);
    if (kh == 0 && (c2 & 1) == 0) {
      __hip_atomic_store(&HG[(jc >> 1) * 32 + b2], mh | (oh << 16),
                         __ATOMIC_RELAXED, __HIP_MEMORY_SCOPE_AGENT);
      A32[((size_t)(b2 * T_ + t) * 512 + jc) >> 1] = ma | (oa << 16);
    }
    grid_barrier(bar, t * 2 + 1);
  }
}

// ---------------- projection: C[2048][32000] = A[2048][512] @ WoutT^T + bout -------
__global__ __launch_bounds__(256) void k_proj(const __hip_bfloat16* __restrict__ Ap,
                                              const __hip_bfloat16* __restrict__ BTp,
                                              const float* __restrict__ bout,
                                              float* __restrict__ C) {
  __shared__ char As[128 * 64 * 2];
  __shared__ char Bs[128 * 64 * 2];
  int tid = threadIdx.x;
  int lane = tid & 63;
  int wave = tid >> 6;
  int m0 = blockIdx.x * 128;
  int n0 = blockIdx.y * 128;
  int wm = wave >> 1, wn = wave & 1;
  f32x4 acc[4][4] = {};

  const char* Ab = (const char*)Ap;
  const char* Bb = (const char*)BTp;

  for (int ks = 0; ks < 8; ++ks) {
    int k0 = ks * 64;
    __syncthreads();
#pragma unroll
    for (int inst = 0; inst < 4; ++inst) {
      int o = inst * 4096 + wave * 1024;
      int ol = o + lane * 16;
      int r = ol >> 7;
      int cb = ol & 127;
      gld_lds16(Ab + ((size_t)(m0 + r) * 512 + k0) * 2 + cb, As + o);
      gld_lds16(Bb + ((size_t)(n0 + r) * 512 + k0) * 2 + cb, Bs + o);
    }
    __syncthreads();
#pragma unroll
    for (int kk = 0; kk < 64; kk += 32) {
      bf16x8 af[4], bfr[4];
      int cbyte = kk * 2 + ((lane >> 4) << 4);
#pragma unroll
      for (int mi = 0; mi < 4; ++mi) {
        int row = wm * 64 + mi * 16 + (lane & 15);
        af[mi] = *(const bf16x8*)(As + row * 128 + cbyte);
      }
#pragma unroll
      for (int ni = 0; ni < 4; ++ni) {
        int row = wn * 64 + ni * 16 + (lane & 15);
        bfr[ni] = *(const bf16x8*)(Bs + row * 128 + cbyte);
      }
#pragma unroll
      for (int mi = 0; mi < 4; ++mi)
#pragma unroll
        for (int ni = 0; ni < 4; ++ni)
          acc[mi][ni] = __builtin_amdgcn_mfma_f32_16x16x32_bf16(af[mi], bfr[ni], acc[mi][ni], 0, 0, 0);
    }
  }
#pragma unroll
  for (int ni = 0; ni < 4; ++ni) {
    int col = n0 + wn * 64 + ni * 16 + (lane & 15);
    float bb = bout[col];
#pragma unroll
    for (int mi = 0; mi < 4; ++mi) {
      int rbase = m0 + wm * 64 + mi * 16 + ((lane >> 4) << 2);
#pragma unroll
      for (int rr = 0; rr < 4; ++rr) {
        C[(size_t)(rbase + rr) * V_ + col] = acc[mi][ni][rr] + bb;
      }
    }
  }
}

extern "C" void kernel_launch(void* const* d_in, const int* in_sizes, int n_in,
                              void* d_out, int out_size, void* d_ws, size_t ws_size,
                              hipStream_t stream) {
  const int* widx = (const int*)d_in[0];
  const int* num_words = (const int*)d_in[1];
  const float* enc = (const float*)d_in[2];
  const float* embW = (const float*)d_in[3];
  const float* Wg = (const float*)d_in[4];
  const float* bg = (const float*)d_in[5];
  const float* Wc = (const float*)d_in[6];
  const float* bc = (const float*)d_in[7];
  const float* Wout = (const float*)d_in[8];
  const float* bout = (const float*)d_in[9];
  float* out = (float*)d_out;

  char* ws = (char*)d_ws;
  float* pre_g = (float*)(ws);                              // 8,388,608
  float* pre_c = (float*)(ws + 8388608);                    // 4,194,304
  __hip_bfloat16* A = (__hip_bfloat16*)(ws + 12582912);     // 2,097,152
  __hip_bfloat16* WoutT = (__hip_bfloat16*)(ws + 14680064); // 32,768,000
  u32t* Wg1 = (u32t*)(ws + 47448064);                       // 1,048,576
  u32t* Wc1 = (u32t*)(ws + 48496640);                       //   524,288
  u32t* RHg = (u32t*)(ws + 49020928);                       //    32,768
  u32t* HG  = (u32t*)(ws + 49053696);                       //    32,768
  u32t* U   = (u32t*)(ws + 49086464);                       //    65,536
  int*  bar = (int*)(ws + 49152000);                        //     1,024

  hipLaunchKernelGGL(k_pack_g1, dim3(1024), dim3(256), 0, stream, Wg, Wg1);
  hipLaunchKernelGGL(k_pack_c1, dim3(512), dim3(256), 0, stream, Wc, Wc1);
  hipLaunchKernelGGL(k_transpose, dim3(500, 8), dim3(256), 0, stream, Wout, WoutT);
  hipLaunchKernelGGL(k_precompute_g, dim3(256, 4), dim3(256), 0, stream,
                     widx, embW, Wg, bg, pre_g);
  hipLaunchKernelGGL(k_precompute_c, dim3(256, 2), dim3(256), 0, stream,
                     widx, embW, Wc, bc, pre_c);
  hipLaunchKernelGGL(k_gru_init, dim3(32), dim3(256), 0, stream, enc, HG, bar);
  hipLaunchKernelGGL(k_gru3, dim3(G_), dim3(512), 0, stream,
                     num_words, Wg1, Wc1, pre_g, pre_c, RHg, HG, U, bar,
                     (u32t*)A);
  hipLaunchKernelGGL(k_proj, dim3(16, 250), dim3(256), 0, stream, A, WoutT, bout, out);
}

// Round 4
// 488.257 us; speedup vs baseline: 5.1080x; 3.4384x over previous
//
#include <hip/hip_runtime.h>
#include <hip/hip_bf16.h>

#define V_ 32000
#define D_ 256
#define H_ 512
#define B_ 32
#define T_ 64
#define NSL 8   // column slices per batch (blocks per batch); grid = 32*NSL = 256

typedef __attribute__((ext_vector_type(8))) __bf16 bf16x8;
typedef __attribute__((ext_vector_type(4))) float f32x4;
typedef _Float16 f16x2 __attribute__((ext_vector_type(2)));
typedef unsigned int u32t;
typedef unsigned long long u64t;

__device__ __forceinline__ u32t pack_h16(float a, float b) {
  union { _Float16 h; unsigned short u; } lo, hi;
  lo.h = (_Float16)a; hi.h = (_Float16)b;
  return (u32t)lo.u | ((u32t)hi.u << 16);
}

__device__ __forceinline__ float dot2(u32t w, u32t h, float acc) {
#if __has_builtin(__builtin_amdgcn_fdot2)
  return __builtin_amdgcn_fdot2(__builtin_bit_cast(f16x2, w),
                                __builtin_bit_cast(f16x2, h), acc, false);
#else
  f16x2 a = __builtin_bit_cast(f16x2, w);
  f16x2 b = __builtin_bit_cast(f16x2, h);
  return acc + (float)a.x * (float)b.x + (float)a.y * (float)b.y;
#endif
}

__device__ __forceinline__ void gld_lds16(const void* g, void* l) {
  __builtin_amdgcn_global_load_lds((const __attribute__((address_space(1))) void*)g,
                                   (__attribute__((address_space(3))) void*)l,
                                   16, 0, 0);
}

// ---------------- Wout [512][32000] f32 -> WoutT [32000][512] bf16 ----------------
__global__ __launch_bounds__(256) void k_transpose(const float* __restrict__ Wout,
                                                   __hip_bfloat16* __restrict__ WoutT) {
  __shared__ float tile[64][65];
  int v0 = blockIdx.x * 64;
  int h0 = blockIdx.y * 64;
  int tid = threadIdx.x;
#pragma unroll
  for (int i = 0; i < 16; ++i) {
    int idx = i * 256 + tid;
    int r = idx >> 6;
    int c = idx & 63;
    tile[r][c] = Wout[(size_t)(h0 + r) * V_ + v0 + c];
  }
  __syncthreads();
#pragma unroll
  for (int i = 0; i < 16; ++i) {
    int idx = i * 256 + tid;
    int rv = idx >> 6;
    int ch = idx & 63;
    WoutT[(size_t)(v0 + rv) * H_ + h0 + ch] = __float2bfloat16(tile[ch][rv]);
  }
}

// ---------------- weight packs for k_gru4 (f16 pairs, per-thread register layouts) ----
// Wg2 uint4 index: ((s*16 + it)*128 + cq)*4 + ks
//   col j = (cq<64) ? s*64+cq : 512 + s*64 + (cq-64);  k-span = ks*128 + it*8 .. +7
__global__ __launch_bounds__(256) void k_pack_g2(const float* __restrict__ Wg,
                                                 uint4* __restrict__ Wg2) {
  int gid = blockIdx.x * 256 + threadIdx.x;  // 0..65535
  int ks = gid & 3;
  int cq = (gid >> 2) & 127;
  int it = (gid >> 9) & 15;
  int s = gid >> 13;
  int j = (cq < 64) ? (s * 64 + cq) : (512 + s * 64 + (cq - 64));
  int k0 = ks * 128 + it * 8;
  uint4 v;
  v.x = pack_h16(Wg[(size_t)(256 + k0 + 0) * 1024 + j], Wg[(size_t)(256 + k0 + 1) * 1024 + j]);
  v.y = pack_h16(Wg[(size_t)(256 + k0 + 2) * 1024 + j], Wg[(size_t)(256 + k0 + 3) * 1024 + j]);
  v.z = pack_h16(Wg[(size_t)(256 + k0 + 4) * 1024 + j], Wg[(size_t)(256 + k0 + 5) * 1024 + j]);
  v.w = pack_h16(Wg[(size_t)(256 + k0 + 6) * 1024 + j], Wg[(size_t)(256 + k0 + 7) * 1024 + j]);
  Wg2[gid] = v;
}
// Wc2 uint4 index: ((s*8 + it)*64 + cq2)*8 + ks8
//   col jc = s*64 + cq2;  k-span = ks8*64 + it*8 .. +7
__global__ __launch_bounds__(256) void k_pack_c2(const float* __restrict__ Wc,
                                                 uint4* __restrict__ Wc2) {
  int gid = blockIdx.x * 256 + threadIdx.x;  // 0..32767
  int ks8 = gid & 7;
  int cq2 = (gid >> 3) & 63;
  int it = (gid >> 9) & 7;
  int s = gid >> 12;
  int jc = s * 64 + cq2;
  int k0 = ks8 * 64 + it * 8;
  uint4 v;
  v.x = pack_h16(Wc[(size_t)(256 + k0 + 0) * 512 + jc], Wc[(size_t)(256 + k0 + 1) * 512 + jc]);
  v.y = pack_h16(Wc[(size_t)(256 + k0 + 2) * 512 + jc], Wc[(size_t)(256 + k0 + 3) * 512 + jc]);
  v.z = pack_h16(Wc[(size_t)(256 + k0 + 4) * 512 + jc], Wc[(size_t)(256 + k0 + 5) * 512 + jc]);
  v.w = pack_h16(Wc[(size_t)(256 + k0 + 6) * 512 + jc], Wc[(size_t)(256 + k0 + 7) * 512 + jc]);
  Wc2[gid] = v;
}

// ---------------- x-projection (gate): pre_g[n][1024] = x_n @ Wg[:256] + bg ----------
__global__ __launch_bounds__(256) void k_precompute_g(const int* __restrict__ widx,
                                                      const float* __restrict__ embW,
                                                      const float* __restrict__ Wg,
                                                      const float* __restrict__ bg,
                                                      float* __restrict__ pre_g) {
  __shared__ __align__(16) float x2[D_][8];
  __shared__ int wid[8];
  int tid = threadIdx.x;
  int n0 = blockIdx.x * 8;
  if (tid < 8) wid[tid] = widx[n0 + tid];
  __syncthreads();
#pragma unroll
  for (int i = 0; i < 8; ++i)
    x2[tid][i] = embW[(size_t)wid[i] * D_ + tid];
  __syncthreads();

  int J = blockIdx.y * 256 + tid;  // 0..1023
  float bias = bg[J];
  float acc[8];
#pragma unroll
  for (int i = 0; i < 8; ++i) acc[i] = bias;
  for (int d = 0; d < D_; ++d) {
    float4 xa = *(const float4*)&x2[d][0];
    float4 xb = *(const float4*)&x2[d][4];
    float w = Wg[(size_t)d * 1024 + J];
    acc[0] = fmaf(xa.x, w, acc[0]); acc[1] = fmaf(xa.y, w, acc[1]);
    acc[2] = fmaf(xa.z, w, acc[2]); acc[3] = fmaf(xa.w, w, acc[3]);
    acc[4] = fmaf(xb.x, w, acc[4]); acc[5] = fmaf(xb.y, w, acc[5]);
    acc[6] = fmaf(xb.z, w, acc[6]); acc[7] = fmaf(xb.w, w, acc[7]);
  }
#pragma unroll
  for (int i = 0; i < 8; ++i)
    pre_g[(size_t)(n0 + i) * 1024 + J] = acc[i];
}

// ---------------- x-projection (cand): pre_c[n][512] = x_n @ Wc[:256] + bc ----------
__global__ __launch_bounds__(256) void k_precompute_c(const int* __restrict__ widx,
                                                      const float* __restrict__ embW,
                                                      const float* __restrict__ Wc,
                                                      const float* __restrict__ bc,
                                                      float* __restrict__ pre_c) {
  __shared__ __align__(16) float x2[D_][8];
  __shared__ int wid[8];
  int tid = threadIdx.x;
  int n0 = blockIdx.x * 8;
  if (tid < 8) wid[tid] = widx[n0 + tid];
  __syncthreads();
#pragma unroll
  for (int i = 0; i < 8; ++i)
    x2[tid][i] = embW[(size_t)wid[i] * D_ + tid];
  __syncthreads();

  int Jc = blockIdx.y * 256 + tid;  // 0..511
  float bias = bc[Jc];
  float acc[8];
#pragma unroll
  for (int i = 0; i < 8; ++i) acc[i] = bias;
  for (int d = 0; d < D_; ++d) {
    float4 xa = *(const float4*)&x2[d][0];
    float4 xb = *(const float4*)&x2[d][4];
    float w = Wc[(size_t)d * 512 + Jc];
    acc[0] = fmaf(xa.x, w, acc[0]); acc[1] = fmaf(xa.y, w, acc[1]);
    acc[2] = fmaf(xa.z, w, acc[2]); acc[3] = fmaf(xa.w, w, acc[3]);
    acc[4] = fmaf(xb.x, w, acc[4]); acc[5] = fmaf(xb.y, w, acc[5]);
    acc[6] = fmaf(xb.z, w, acc[6]); acc[7] = fmaf(xb.w, w, acc[7]);
  }
#pragma unroll
  for (int i = 0; i < 8; ++i)
    pre_c[(size_t)(n0 + i) * 512 + Jc] = acc[i];
}

// ---------------- GRU init: HB[b][wk] = packed f16 pair of enc; zero barriers ----------
__global__ __launch_bounds__(256) void k_gru_init(const float* __restrict__ enc,
                                                  u32t* __restrict__ HB,
                                                  int* __restrict__ bar) {
  int gid = blockIdx.x * 256 + threadIdx.x;  // 0..8191
  int b = gid >> 8, wk = gid & 255;
  u32t v = pack_h16(enc[b * H_ + 2 * wk], enc[b * H_ + 2 * wk + 1]);
  __hip_atomic_store(&HB[gid], v, __ATOMIC_RELAXED, __HIP_MEMORY_SCOPE_AGENT);
  if (gid < 2048)
    __hip_atomic_store(&bar[gid], 0, __ATOMIC_RELAXED, __HIP_MEMORY_SCOPE_AGENT);
}

// ---------------- GRU v4: 256 blocks = 32 batches x 8 col-slices; weights in VGPRs ----
// block (b, s): owns gate cols {s*64..s*64+63} (r) and {512+s*64..} (u),
//               cand cols {s*64..s*64+63}. u stays block-local.
// Cross-block per phase: rh / h slices (128B out, 1KB in) via relaxed agent (sc1) ops.
// Barrier: per-batch monotonic counter, relaxed atomics only (no cache invalidation);
// ordering via __syncthreads() vmcnt drain before the flag add.
__global__ __launch_bounds__(512, 2) void k_gru4(const int* __restrict__ num_words,
                                                 const uint4* __restrict__ Wg2,
                                                 const uint4* __restrict__ Wc2,
                                                 const float* __restrict__ pre_g,
                                                 const float* __restrict__ pre_c,
                                                 u32t* __restrict__ RH,
                                                 u32t* __restrict__ HB,
                                                 int* __restrict__ bar,
                                                 u32t* __restrict__ A32) {
  __shared__ __align__(16) u32t h2_l[256];
  __shared__ __align__(16) u32t rh2_l[256];
  __shared__ float u_l[64];
  int bid = blockIdx.x;
  int b = bid & 31;
  int s = bid >> 5;
  int tid = threadIdx.x;
  int nw = num_words[b];
  int* mybar = bar + b * 64;  // 256B-spaced counter lines

  // phase-1 mapping: 128 gate cols x 4-way K-split
  int cq = tid >> 2, ks = tid & 3;
  int j1 = (cq < 64) ? (s * 64 + cq) : (512 + s * 64 + (cq - 64));
  // phase-2 mapping: 64 cand cols x 8-way K-split
  int cq2 = tid >> 3, ks8 = tid & 7;
  int jc = s * 64 + cq2;

  // ---- weights -> registers, fixed for all 64 steps ----
  uint4 wg[16];
#pragma unroll
  for (int i = 0; i < 16; ++i)
    wg[i] = Wg2[(((size_t)s * 16 + i) * 128 + cq) * 4 + ks];
  uint4 wc[8];
#pragma unroll
  for (int i = 0; i < 8; ++i)
    wc[i] = Wc2[(((size_t)s * 8 + i) * 64 + cq2) * 8 + ks8];

  const u64t* HB64 = (const u64t*)HB;
  const u64t* RH64 = (const u64t*)RH;

  for (int t = 0; t < T_; ++t) {
    // ---- stage full h of batch b (1KB) ----
    if (tid < 64) {
      u64t v = __hip_atomic_load(&HB64[(size_t)b * 128 + 2 * tid], __ATOMIC_RELAXED,
                                 __HIP_MEMORY_SCOPE_AGENT);
      u64t v2 = __hip_atomic_load(&HB64[(size_t)b * 128 + 2 * tid + 1], __ATOMIC_RELAXED,
                                  __HIP_MEMORY_SCOPE_AGENT);
      *(u64t*)&h2_l[4 * tid] = v;
      *(u64t*)&h2_l[4 * tid + 2] = v2;
    }
    __syncthreads();

    // ---- phase 1: gates ----
    float pg = pre_g[((size_t)b * T_ + t) * 1024 + j1];
    float a = 0.f;
    const uint4* h4 = (const uint4*)h2_l;
#pragma unroll
    for (int i = 0; i < 16; ++i) {
      uint4 hv = h4[ks * 16 + i];
      a = dot2(wg[i].x, hv.x, a);
      a = dot2(wg[i].y, hv.y, a);
      a = dot2(wg[i].z, hv.z, a);
      a = dot2(wg[i].w, hv.w, a);
    }
    a += __shfl_xor(a, 1);
    a += __shfl_xor(a, 2);
    float gate = 1.f / (1.f + __expf(-(a + pg)));
    if (cq < 64) {  // r-gate: publish rh slice (waves 0..3 fully active)
      u32t hw = h2_l[(s * 64 + cq) >> 1];
      f16x2 hp = __builtin_bit_cast(f16x2, hw);
      float hh = (cq & 1) ? (float)hp.y : (float)hp.x;
      u32t mine = pack_h16(gate * hh, 0.f) & 0xffffu;
      u32t oth = (u32t)__shfl_xor((int)mine, 4);
      if (ks == 0 && (cq & 1) == 0)
        __hip_atomic_store(&RH[(size_t)b * 256 + s * 32 + (cq >> 1)],
                           mine | (oth << 16), __ATOMIC_RELAXED,
                           __HIP_MEMORY_SCOPE_AGENT);
    } else if (ks == 0) {  // u-gate stays local
      u_l[cq - 64] = gate;
    }

    // ---- barrier 1 (rh ready) ----
    asm volatile("s_waitcnt vmcnt(0)" ::: "memory");
    __syncthreads();
    if (tid == 0) {
      __hip_atomic_fetch_add(mybar, 1, __ATOMIC_RELAXED, __HIP_MEMORY_SCOPE_AGENT);
      int tgt = NSL * (2 * t + 1);
      while (__hip_atomic_load(mybar, __ATOMIC_RELAXED, __HIP_MEMORY_SCOPE_AGENT) < tgt)
        __builtin_amdgcn_s_sleep(1);
    }
    __syncthreads();
    asm volatile("" ::: "memory");

    // ---- stage full rh (1KB) ----
    if (tid < 64) {
      u64t v = __hip_atomic_load(&RH64[(size_t)b * 128 + 2 * tid], __ATOMIC_RELAXED,
                                 __HIP_MEMORY_SCOPE_AGENT);
      u64t v2 = __hip_atomic_load(&RH64[(size_t)b * 128 + 2 * tid + 1], __ATOMIC_RELAXED,
                                  __HIP_MEMORY_SCOPE_AGENT);
      *(u64t*)&rh2_l[4 * tid] = v;
      *(u64t*)&rh2_l[4 * tid + 2] = v2;
    }
    __syncthreads();

    // ---- phase 2: candidate + state update ----
    float a2 = 0.f;
    const uint4* r4 = (const uint4*)rh2_l;
#pragma unroll
    for (int i = 0; i < 8; ++i) {
      uint4 rv = r4[ks8 * 8 + i];
      a2 = dot2(wc[i].x, rv.x, a2);
      a2 = dot2(wc[i].y, rv.y, a2);
      a2 = dot2(wc[i].z, rv.z, a2);
      a2 = dot2(wc[i].w, rv.w, a2);
    }
    a2 += __shfl_xor(a2, 1);
    a2 += __shfl_xor(a2, 2);
    a2 += __shfl_xor(a2, 4);
    float pc = pre_c[((size_t)b * T_ + t) * 512 + jc];
    float cv = tanhf(a2 + pc);
    float uu = u_l[cq2];
    u32t hw = h2_l[jc >> 1];
    f16x2 hp = __builtin_bit_cast(f16x2, hw);
    float hold = (cq2 & 1) ? (float)hp.y : (float)hp.x;
    float hn = uu * hold + (1.f - uu) * cv;
    bool live = t < nw;
    float hnext = live ? hn : hold;
    u32t mh = pack_h16(hnext, 0.f) & 0xffffu;
    u32t ma = (u32t)__hip_bfloat16_raw(__float2bfloat16(live ? hn : 0.f)).x;
    u32t oh = (u32t)__shfl_xor((int)mh, 8);
    u32t oa = (u32t)__shfl_xor((int)ma, 8);
    if (ks8 == 0 && (cq2 & 1) == 0) {
      __hip_atomic_store(&HB[(size_t)b * 256 + s * 32 + (cq2 >> 1)],
                         mh | (oh << 16), __ATOMIC_RELAXED, __HIP_MEMORY_SCOPE_AGENT);
      A32[(((size_t)b * T_ + t) * 512 + jc) >> 1] = ma | (oa << 16);
    }

    // ---- barrier 2 (h ready) ----
    asm volatile("s_waitcnt vmcnt(0)" ::: "memory");
    __syncthreads();
    if (tid == 0) {
      __hip_atomic_fetch_add(mybar, 1, __ATOMIC_RELAXED, __HIP_MEMORY_SCOPE_AGENT);
      int tgt = NSL * (2 * t + 2);
      while (__hip_atomic_load(mybar, __ATOMIC_RELAXED, __HIP_MEMORY_SCOPE_AGENT) < tgt)
        __builtin_amdgcn_s_sleep(1);
    }
    __syncthreads();
    asm volatile("" ::: "memory");
  }
}

// ---------------- projection: C[2048][32000] = A[2048][512] @ WoutT^T + bout -------
__global__ __launch_bounds__(256) void k_proj(const __hip_bfloat16* __restrict__ Ap,
                                              const __hip_bfloat16* __restrict__ BTp,
                                              const float* __restrict__ bout,
                                              float* __restrict__ C) {
  __shared__ char As[128 * 64 * 2];
  __shared__ char Bs[128 * 64 * 2];
  int tid = threadIdx.x;
  int lane = tid & 63;
  int wave = tid >> 6;
  int m0 = blockIdx.x * 128;
  int n0 = blockIdx.y * 128;
  int wm = wave >> 1, wn = wave & 1;
  f32x4 acc[4][4] = {};

  const char* Ab = (const char*)Ap;
  const char* Bb = (const char*)BTp;

  for (int ks = 0; ks < 8; ++ks) {
    int k0 = ks * 64;
    __syncthreads();
#pragma unroll
    for (int inst = 0; inst < 4; ++inst) {
      int o = inst * 4096 + wave * 1024;
      int ol = o + lane * 16;
      int r = ol >> 7;
      int cb = ol & 127;
      gld_lds16(Ab + ((size_t)(m0 + r) * 512 + k0) * 2 + cb, As + o);
      gld_lds16(Bb + ((size_t)(n0 + r) * 512 + k0) * 2 + cb, Bs + o);
    }
    __syncthreads();
#pragma unroll
    for (int kk = 0; kk < 64; kk += 32) {
      bf16x8 af[4], bfr[4];
      int cbyte = kk * 2 + ((lane >> 4) << 4);
#pragma unroll
      for (int mi = 0; mi < 4; ++mi) {
        int row = wm * 64 + mi * 16 + (lane & 15);
        af[mi] = *(const bf16x8*)(As + row * 128 + cbyte);
      }
#pragma unroll
      for (int ni = 0; ni < 4; ++ni) {
        int row = wn * 64 + ni * 16 + (lane & 15);
        bfr[ni] = *(const bf16x8*)(Bs + row * 128 + cbyte);
      }
#pragma unroll
      for (int mi = 0; mi < 4; ++mi)
#pragma unroll
        for (int ni = 0; ni < 4; ++ni)
          acc[mi][ni] = __builtin_amdgcn_mfma_f32_16x16x32_bf16(af[mi], bfr[ni], acc[mi][ni], 0, 0, 0);
    }
  }
#pragma unroll
  for (int ni = 0; ni < 4; ++ni) {
    int col = n0 + wn * 64 + ni * 16 + (lane & 15);
    float bb = bout[col];
#pragma unroll
    for (int mi = 0; mi < 4; ++mi) {
      int rbase = m0 + wm * 64 + mi * 16 + ((lane >> 4) << 2);
#pragma unroll
      for (int rr = 0; rr < 4; ++rr) {
        C[(size_t)(rbase + rr) * V_ + col] = acc[mi][ni][rr] + bb;
      }
    }
  }
}

extern "C" void kernel_launch(void* const* d_in, const int* in_sizes, int n_in,
                              void* d_out, int out_size, void* d_ws, size_t ws_size,
                              hipStream_t stream) {
  const int* widx = (const int*)d_in[0];
  const int* num_words = (const int*)d_in[1];
  const float* enc = (const float*)d_in[2];
  const float* embW = (const float*)d_in[3];
  const float* Wg = (const float*)d_in[4];
  const float* bg = (const float*)d_in[5];
  const float* Wc = (const float*)d_in[6];
  const float* bc = (const float*)d_in[7];
  const float* Wout = (const float*)d_in[8];
  const float* bout = (const float*)d_in[9];
  float* out = (float*)d_out;

  char* ws = (char*)d_ws;
  float* pre_g = (float*)(ws);                              // 8,388,608
  float* pre_c = (float*)(ws + 8388608);                    // 4,194,304
  __hip_bfloat16* A = (__hip_bfloat16*)(ws + 12582912);     // 2,097,152
  __hip_bfloat16* WoutT = (__hip_bfloat16*)(ws + 14680064); // 32,768,000
  uint4* Wg2 = (uint4*)(ws + 47448064);                     // 1,048,576
  uint4* Wc2 = (uint4*)(ws + 48496640);                     //   524,288
  u32t* RH = (u32t*)(ws + 49020928);                        //    32,768
  u32t* HB = (u32t*)(ws + 49053696);                        //    32,768
  int* bar = (int*)(ws + 49086464);                         //     8,192

  hipLaunchKernelGGL(k_pack_g2, dim3(256), dim3(256), 0, stream, Wg, Wg2);
  hipLaunchKernelGGL(k_pack_c2, dim3(128), dim3(256), 0, stream, Wc, Wc2);
  hipLaunchKernelGGL(k_transpose, dim3(500, 8), dim3(256), 0, stream, Wout, WoutT);
  hipLaunchKernelGGL(k_precompute_g, dim3(256, 4), dim3(256), 0, stream,
                     widx, embW, Wg, bg, pre_g);
  hipLaunchKernelGGL(k_precompute_c, dim3(256, 2), dim3(256), 0, stream,
                     widx, embW, Wc, bc, pre_c);
  hipLaunchKernelGGL(k_gru_init, dim3(32), dim3(256), 0, stream, enc, HB, bar);
  hipLaunchKernelGGL(k_gru4, dim3(32 * NSL), dim3(512), 0, stream,
                     num_words, Wg2, Wc2, pre_g, pre_c, RH, HB, bar, (u32t*)A);
  hipLaunchKernelGGL(k_proj, dim3(16, 250), dim3(256), 0, stream, A, WoutT, bout, out);
}

// Round 5
// 446.806 us; speedup vs baseline: 5.5818x; 1.0928x over previous
//
#include <hip/hip_runtime.h>
#include <hip/hip_bf16.h>

#define V_ 32000
#define D_ 256
#define H_ 512
#define B_ 32
#define T_ 64
#define NSL 8   // column slices per batch; GRU grid = 32*NSL = 256

typedef __attribute__((ext_vector_type(8))) __bf16 bf16x8;
typedef __attribute__((ext_vector_type(4))) float f32x4;
typedef _Float16 f16x2 __attribute__((ext_vector_type(2)));
typedef unsigned int u32t;
typedef unsigned long long u64t;

__device__ __forceinline__ u32t pack_h16(float a, float b) {
  union { _Float16 h; unsigned short u; } lo, hi;
  lo.h = (_Float16)a; hi.h = (_Float16)b;
  return (u32t)lo.u | ((u32t)hi.u << 16);
}

__device__ __forceinline__ float dot2(u32t w, u32t h, float acc) {
#if __has_builtin(__builtin_amdgcn_fdot2)
  return __builtin_amdgcn_fdot2(__builtin_bit_cast(f16x2, w),
                                __builtin_bit_cast(f16x2, h), acc, false);
#else
  f16x2 a = __builtin_bit_cast(f16x2, w);
  f16x2 b = __builtin_bit_cast(f16x2, h);
  return acc + (float)a.x * (float)b.x + (float)a.y * (float)b.y;
#endif
}

__device__ __forceinline__ void gld_lds16(const void* g, void* l) {
  __builtin_amdgcn_global_load_lds((const __attribute__((address_space(1))) void*)g,
                                   (__attribute__((address_space(3))) void*)l,
                                   16, 0, 0);
}

// ---------------- Wout [512][32000] f32 -> WoutT [32000][512] bf16 ----------------
__global__ __launch_bounds__(256) void k_transpose(const float* __restrict__ Wout,
                                                   __hip_bfloat16* __restrict__ WoutT) {
  __shared__ float tile[64][65];
  int v0 = blockIdx.x * 64;
  int h0 = blockIdx.y * 64;
  int tid = threadIdx.x;
#pragma unroll
  for (int i = 0; i < 16; ++i) {
    int idx = i * 256 + tid;
    int r = idx >> 6;
    int c = idx & 63;
    tile[r][c] = Wout[(size_t)(h0 + r) * V_ + v0 + c];
  }
  __syncthreads();
#pragma unroll
  for (int i = 0; i < 16; ++i) {
    int idx = i * 256 + tid;
    int rv = idx >> 6;
    int ch = idx & 63;
    WoutT[(size_t)(v0 + rv) * H_ + h0 + ch] = __float2bfloat16(tile[ch][rv]);
  }
}

// ---------------- weight packs (f16 pairs, per-thread register layouts) ----------
// Wg2 uint4 index: ((s*16 + it)*128 + cq)*4 + ks
//   col j = (cq<64) ? s*64+cq : 512 + s*64 + (cq-64);  k-span = ks*128 + it*8 .. +7
__global__ __launch_bounds__(256) void k_pack_g2(const float* __restrict__ Wg,
                                                 uint4* __restrict__ Wg2) {
  int gid = blockIdx.x * 256 + threadIdx.x;  // 0..65535
  int ks = gid & 3;
  int cq = (gid >> 2) & 127;
  int it = (gid >> 9) & 15;
  int s = gid >> 13;
  int j = (cq < 64) ? (s * 64 + cq) : (512 + s * 64 + (cq - 64));
  int k0 = ks * 128 + it * 8;
  uint4 v;
  v.x = pack_h16(Wg[(size_t)(256 + k0 + 0) * 1024 + j], Wg[(size_t)(256 + k0 + 1) * 1024 + j]);
  v.y = pack_h16(Wg[(size_t)(256 + k0 + 2) * 1024 + j], Wg[(size_t)(256 + k0 + 3) * 1024 + j]);
  v.z = pack_h16(Wg[(size_t)(256 + k0 + 4) * 1024 + j], Wg[(size_t)(256 + k0 + 5) * 1024 + j]);
  v.w = pack_h16(Wg[(size_t)(256 + k0 + 6) * 1024 + j], Wg[(size_t)(256 + k0 + 7) * 1024 + j]);
  Wg2[gid] = v;
}
// Wc2 uint4 index: ((s*8 + it)*64 + cq2)*8 + ks8 ; col jc = s*64+cq2; k-span ks8*64+it*8..+7
__global__ __launch_bounds__(256) void k_pack_c2(const float* __restrict__ Wc,
                                                 uint4* __restrict__ Wc2) {
  int gid = blockIdx.x * 256 + threadIdx.x;  // 0..32767
  int ks8 = gid & 7;
  int cq2 = (gid >> 3) & 63;
  int it = (gid >> 9) & 7;
  int s = gid >> 12;
  int jc = s * 64 + cq2;
  int k0 = ks8 * 64 + it * 8;
  uint4 v;
  v.x = pack_h16(Wc[(size_t)(256 + k0 + 0) * 512 + jc], Wc[(size_t)(256 + k0 + 1) * 512 + jc]);
  v.y = pack_h16(Wc[(size_t)(256 + k0 + 2) * 512 + jc], Wc[(size_t)(256 + k0 + 3) * 512 + jc]);
  v.z = pack_h16(Wc[(size_t)(256 + k0 + 4) * 512 + jc], Wc[(size_t)(256 + k0 + 5) * 512 + jc]);
  v.w = pack_h16(Wc[(size_t)(256 + k0 + 6) * 512 + jc], Wc[(size_t)(256 + k0 + 7) * 512 + jc]);
  Wc2[gid] = v;
}

// ---------------- x-projection (gate): pre_g[n][1024] = x_n @ Wg[:256] + bg ----------
__global__ __launch_bounds__(256) void k_precompute_g(const int* __restrict__ widx,
                                                      const float* __restrict__ embW,
                                                      const float* __restrict__ Wg,
                                                      const float* __restrict__ bg,
                                                      float* __restrict__ pre_g) {
  __shared__ __align__(16) float x2[D_][8];
  __shared__ int wid[8];
  int tid = threadIdx.x;
  int n0 = blockIdx.x * 8;
  if (tid < 8) wid[tid] = widx[n0 + tid];
  __syncthreads();
#pragma unroll
  for (int i = 0; i < 8; ++i)
    x2[tid][i] = embW[(size_t)wid[i] * D_ + tid];
  __syncthreads();

  int J = blockIdx.y * 256 + tid;  // 0..1023
  float bias = bg[J];
  float acc[8];
#pragma unroll
  for (int i = 0; i < 8; ++i) acc[i] = bias;
  for (int d = 0; d < D_; ++d) {
    float4 xa = *(const float4*)&x2[d][0];
    float4 xb = *(const float4*)&x2[d][4];
    float w = Wg[(size_t)d * 1024 + J];
    acc[0] = fmaf(xa.x, w, acc[0]); acc[1] = fmaf(xa.y, w, acc[1]);
    acc[2] = fmaf(xa.z, w, acc[2]); acc[3] = fmaf(xa.w, w, acc[3]);
    acc[4] = fmaf(xb.x, w, acc[4]); acc[5] = fmaf(xb.y, w, acc[5]);
    acc[6] = fmaf(xb.z, w, acc[6]); acc[7] = fmaf(xb.w, w, acc[7]);
  }
#pragma unroll
  for (int i = 0; i < 8; ++i)
    pre_g[(size_t)(n0 + i) * 1024 + J] = acc[i];
}

// ---------------- x-projection (cand): pre_c[n][512] = x_n @ Wc[:256] + bc ----------
__global__ __launch_bounds__(256) void k_precompute_c(const int* __restrict__ widx,
                                                      const float* __restrict__ embW,
                                                      const float* __restrict__ Wc,
                                                      const float* __restrict__ bc,
                                                      float* __restrict__ pre_c) {
  __shared__ __align__(16) float x2[D_][8];
  __shared__ int wid[8];
  int tid = threadIdx.x;
  int n0 = blockIdx.x * 8;
  if (tid < 8) wid[tid] = widx[n0 + tid];
  __syncthreads();
#pragma unroll
  for (int i = 0; i < 8; ++i)
    x2[tid][i] = embW[(size_t)wid[i] * D_ + tid];
  __syncthreads();

  int Jc = blockIdx.y * 256 + tid;  // 0..511
  float bias = bc[Jc];
  float acc[8];
#pragma unroll
  for (int i = 0; i < 8; ++i) acc[i] = bias;
  for (int d = 0; d < D_; ++d) {
    float4 xa = *(const float4*)&x2[d][0];
    float4 xb = *(const float4*)&x2[d][4];
    float w = Wc[(size_t)d * 512 + Jc];
    acc[0] = fmaf(xa.x, w, acc[0]); acc[1] = fmaf(xa.y, w, acc[1]);
    acc[2] = fmaf(xa.z, w, acc[2]); acc[3] = fmaf(xa.w, w, acc[3]);
    acc[4] = fmaf(xb.x, w, acc[4]); acc[5] = fmaf(xb.y, w, acc[5]);
    acc[6] = fmaf(xb.z, w, acc[6]); acc[7] = fmaf(xb.w, w, acc[7]);
  }
#pragma unroll
  for (int i = 0; i < 8; ++i)
    pre_c[(size_t)(n0 + i) * 512 + Jc] = acc[i];
}

// ---------------- GRU init: HB[b][wk] = packed f16 pair of enc; zero flags ----------
__global__ __launch_bounds__(256) void k_gru_init(const float* __restrict__ enc,
                                                  u32t* __restrict__ HB,
                                                  int* __restrict__ flags) {
  int gid = blockIdx.x * 256 + threadIdx.x;  // 0..8191
  int b = gid >> 8, wk = gid & 255;
  u32t v = pack_h16(enc[b * H_ + 2 * wk], enc[b * H_ + 2 * wk + 1]);
  __hip_atomic_store(&HB[gid], v, __ATOMIC_RELAXED, __HIP_MEMORY_SCOPE_AGENT);
#pragma unroll
  for (int i = 0; i < 4; ++i)
    __hip_atomic_store(&flags[gid * 4 + i], 0, __ATOMIC_RELAXED, __HIP_MEMORY_SCOPE_AGENT);
}

// ---------------- GRU v5: 256 blocks = 32 batches x 8 slices; weights in VGPRs ------
// Sync: per-(b,s) monotonic flags (256B-spaced), relaxed agent atomics only.
// Publisher: payload stores -> vmcnt(0) drain -> flag store (fire-and-forget).
// Consumer: 8 lanes poll the 8 slice flags in parallel, then stage payload.
// LDS reads bank-derotated: chunk ii=(i+ksplit)&mask so K-split groups hit disjoint banks.
__global__ __launch_bounds__(512, 2) void k_gru5(const int* __restrict__ num_words,
                                                 const uint4* __restrict__ Wg2,
                                                 const uint4* __restrict__ Wc2,
                                                 const float* __restrict__ pre_g,
                                                 const float* __restrict__ pre_c,
                                                 u32t* __restrict__ RH,
                                                 u32t* __restrict__ HB,
                                                 int* __restrict__ flagR,
                                                 int* __restrict__ flagH,
                                                 u32t* __restrict__ A32) {
  __shared__ __align__(16) u32t h2_l[256];
  __shared__ __align__(16) u32t rh2_l[256];
  __shared__ float u_l[64];
  int bid = blockIdx.x;
  int b = bid & 31;
  int s = bid >> 5;
  int tid = threadIdx.x;
  int nw = num_words[b];

  // phase-1 mapping: 128 gate cols x 4-way K-split
  int cq = tid >> 2, ks = tid & 3;
  int j1 = (cq < 64) ? (s * 64 + cq) : (512 + s * 64 + (cq - 64));
  // phase-2 mapping: 64 cand cols x 8-way K-split
  int cq2 = tid >> 3, ks8 = tid & 7;
  int jc = s * 64 + cq2;

  // ---- weights -> registers (pre-rotated: wg[i] holds k-chunk (i+ks)&15) ----
  uint4 wg[16];
#pragma unroll
  for (int i = 0; i < 16; ++i) {
    int ii = (i + ks) & 15;
    wg[i] = Wg2[(((size_t)s * 16 + ii) * 128 + cq) * 4 + ks];
  }
  uint4 wc[8];
#pragma unroll
  for (int i = 0; i < 8; ++i) {
    int ii = (i + ks8) & 7;
    wc[i] = Wc2[(((size_t)s * 8 + ii) * 64 + cq2) * 8 + ks8];
  }

  const u64t* HB64 = (const u64t*)HB;
  const u64t* RH64 = (const u64t*)RH;
  int* fR = flagR + b * 512;  // + s*64 per slice (256B spacing)
  int* fH = flagH + b * 512;

  for (int t = 0; t < T_; ++t) {
    // hoisted streamed loads (off the post-barrier critical path)
    float pg = pre_g[((size_t)b * T_ + t) * 1024 + j1];
    float pc = pre_c[((size_t)b * T_ + t) * 512 + jc];

    // ---- stage full h of batch b (1KB) ----
    if (tid < 64) {
      u64t v = __hip_atomic_load(&HB64[(size_t)b * 128 + 2 * tid], __ATOMIC_RELAXED,
                                 __HIP_MEMORY_SCOPE_AGENT);
      u64t v2 = __hip_atomic_load(&HB64[(size_t)b * 128 + 2 * tid + 1], __ATOMIC_RELAXED,
                                  __HIP_MEMORY_SCOPE_AGENT);
      *(u64t*)&h2_l[4 * tid] = v;
      *(u64t*)&h2_l[4 * tid + 2] = v2;
    }
    __syncthreads();

    // ---- phase 1: gates (bank-derotated LDS reads) ----
    float a = 0.f;
    const uint4* h4 = (const uint4*)h2_l;
#pragma unroll
    for (int i = 0; i < 16; ++i) {
      int ii = (i + ks) & 15;
      uint4 hv = h4[ks * 16 + ii];
      a = dot2(wg[i].x, hv.x, a);
      a = dot2(wg[i].y, hv.y, a);
      a = dot2(wg[i].z, hv.z, a);
      a = dot2(wg[i].w, hv.w, a);
    }
    a += __shfl_xor(a, 1);
    a += __shfl_xor(a, 2);
    float gate = 1.f / (1.f + __expf(-(a + pg)));
    if (cq < 64) {  // r-gate: publish rh slice
      u32t hw = h2_l[(s * 64 + cq) >> 1];
      f16x2 hp = __builtin_bit_cast(f16x2, hw);
      float hh = (cq & 1) ? (float)hp.y : (float)hp.x;
      u32t mine = pack_h16(gate * hh, 0.f) & 0xffffu;
      u32t oth = (u32t)__shfl_xor((int)mine, 4);
      if (ks == 0 && (cq & 1) == 0)
        __hip_atomic_store(&RH[(size_t)b * 256 + s * 32 + (cq >> 1)],
                           mine | (oth << 16), __ATOMIC_RELAXED,
                           __HIP_MEMORY_SCOPE_AGENT);
    } else if (ks == 0) {  // u-gate stays block-local
      u_l[cq - 64] = gate;
    }

    // ---- sync 1: rh ready ----
    asm volatile("s_waitcnt vmcnt(0)" ::: "memory");
    __syncthreads();
    if (tid == 0)
      __hip_atomic_store(&fR[s * 64], t + 1, __ATOMIC_RELAXED, __HIP_MEMORY_SCOPE_AGENT);
    if (tid < NSL) {
      while (__hip_atomic_load(&fR[tid * 64], __ATOMIC_RELAXED, __HIP_MEMORY_SCOPE_AGENT) < t + 1)
        __builtin_amdgcn_s_sleep(1);
    }
    __syncthreads();

    // ---- stage full rh (1KB) ----
    if (tid < 64) {
      u64t v = __hip_atomic_load(&RH64[(size_t)b * 128 + 2 * tid], __ATOMIC_RELAXED,
                                 __HIP_MEMORY_SCOPE_AGENT);
      u64t v2 = __hip_atomic_load(&RH64[(size_t)b * 128 + 2 * tid + 1], __ATOMIC_RELAXED,
                                  __HIP_MEMORY_SCOPE_AGENT);
      *(u64t*)&rh2_l[4 * tid] = v;
      *(u64t*)&rh2_l[4 * tid + 2] = v2;
    }
    __syncthreads();

    // ---- phase 2: candidate + state update (bank-derotated) ----
    float a2 = 0.f;
    const uint4* r4 = (const uint4*)rh2_l;
#pragma unroll
    for (int i = 0; i < 8; ++i) {
      int ii = (i + ks8) & 7;
      uint4 rv = r4[ks8 * 8 + ii];
      a2 = dot2(wc[i].x, rv.x, a2);
      a2 = dot2(wc[i].y, rv.y, a2);
      a2 = dot2(wc[i].z, rv.z, a2);
      a2 = dot2(wc[i].w, rv.w, a2);
    }
    a2 += __shfl_xor(a2, 1);
    a2 += __shfl_xor(a2, 2);
    a2 += __shfl_xor(a2, 4);
    float cv = tanhf(a2 + pc);
    float uu = u_l[cq2];
    u32t hw = h2_l[jc >> 1];
    f16x2 hp = __builtin_bit_cast(f16x2, hw);
    float hold = (cq2 & 1) ? (float)hp.y : (float)hp.x;
    float hn = uu * hold + (1.f - uu) * cv;
    bool live = t < nw;
    float hnext = live ? hn : hold;
    u32t mh = pack_h16(hnext, 0.f) & 0xffffu;
    u32t ma = (u32t)__hip_bfloat16_raw(__float2bfloat16(live ? hn : 0.f)).x;
    u32t oh = (u32t)__shfl_xor((int)mh, 8);
    u32t oa = (u32t)__shfl_xor((int)ma, 8);
    bool writer = (ks8 == 0) && ((cq2 & 1) == 0);
    if (writer)
      __hip_atomic_store(&HB[(size_t)b * 256 + s * 32 + (cq2 >> 1)],
                         mh | (oh << 16), __ATOMIC_RELAXED, __HIP_MEMORY_SCOPE_AGENT);

    // ---- sync 2: h ready (A-store deferred past the flag, off the drain path) ----
    asm volatile("s_waitcnt vmcnt(0)" ::: "memory");
    __syncthreads();
    if (tid == 0)
      __hip_atomic_store(&fH[s * 64], t + 1, __ATOMIC_RELAXED, __HIP_MEMORY_SCOPE_AGENT);
    if (writer)
      A32[(((size_t)b * T_ + t) * 512 + jc) >> 1] = ma | (oa << 16);
    if (tid < NSL) {
      while (__hip_atomic_load(&fH[tid * 64], __ATOMIC_RELAXED, __HIP_MEMORY_SCOPE_AGENT) < t + 1)
        __builtin_amdgcn_s_sleep(1);
    }
    __syncthreads();
  }
}

// ---------------- projection: C[2048][32000] = A[2048][512] @ WoutT^T + bout -------
__global__ __launch_bounds__(256) void k_proj(const __hip_bfloat16* __restrict__ Ap,
                                              const __hip_bfloat16* __restrict__ BTp,
                                              const float* __restrict__ bout,
                                              float* __restrict__ C) {
  __shared__ char As[128 * 64 * 2];
  __shared__ char Bs[128 * 64 * 2];
  int tid = threadIdx.x;
  int lane = tid & 63;
  int wave = tid >> 6;
  int m0 = blockIdx.x * 128;
  int n0 = blockIdx.y * 128;
  int wm = wave >> 1, wn = wave & 1;
  f32x4 acc[4][4] = {};

  const char* Ab = (const char*)Ap;
  const char* Bb = (const char*)BTp;

  for (int ks = 0; ks < 8; ++ks) {
    int k0 = ks * 64;
    __syncthreads();
#pragma unroll
    for (int inst = 0; inst < 4; ++inst) {
      int o = inst * 4096 + wave * 1024;
      int ol = o + lane * 16;
      int r = ol >> 7;
      int cb = ol & 127;
      gld_lds16(Ab + ((size_t)(m0 + r) * 512 + k0) * 2 + cb, As + o);
      gld_lds16(Bb + ((size_t)(n0 + r) * 512 + k0) * 2 + cb, Bs + o);
    }
    __syncthreads();
#pragma unroll
    for (int kk = 0; kk < 64; kk += 32) {
      bf16x8 af[4], bfr[4];
      int cbyte = kk * 2 + ((lane >> 4) << 4);
#pragma unroll
      for (int mi = 0; mi < 4; ++mi) {
        int row = wm * 64 + mi * 16 + (lane & 15);
        af[mi] = *(const bf16x8*)(As + row * 128 + cbyte);
      }
#pragma unroll
      for (int ni = 0; ni < 4; ++ni) {
        int row = wn * 64 + ni * 16 + (lane & 15);
        bfr[ni] = *(const bf16x8*)(Bs + row * 128 + cbyte);
      }
#pragma unroll
      for (int mi = 0; mi < 4; ++mi)
#pragma unroll
        for (int ni = 0; ni < 4; ++ni)
          acc[mi][ni] = __builtin_amdgcn_mfma_f32_16x16x32_bf16(af[mi], bfr[ni], acc[mi][ni], 0, 0, 0);
    }
  }
#pragma unroll
  for (int ni = 0; ni < 4; ++ni) {
    int col = n0 + wn * 64 + ni * 16 + (lane & 15);
    float bb = bout[col];
#pragma unroll
    for (int mi = 0; mi < 4; ++mi) {
      int rbase = m0 + wm * 64 + mi * 16 + ((lane >> 4) << 2);
#pragma unroll
      for (int rr = 0; rr < 4; ++rr) {
        C[(size_t)(rbase + rr) * V_ + col] = acc[mi][ni][rr] + bb;
      }
    }
  }
}

extern "C" void kernel_launch(void* const* d_in, const int* in_sizes, int n_in,
                              void* d_out, int out_size, void* d_ws, size_t ws_size,
                              hipStream_t stream) {
  const int* widx = (const int*)d_in[0];
  const int* num_words = (const int*)d_in[1];
  const float* enc = (const float*)d_in[2];
  const float* embW = (const float*)d_in[3];
  const float* Wg = (const float*)d_in[4];
  const float* bg = (const float*)d_in[5];
  const float* Wc = (const float*)d_in[6];
  const float* bc = (const float*)d_in[7];
  const float* Wout = (const float*)d_in[8];
  const float* bout = (const float*)d_in[9];
  float* out = (float*)d_out;

  char* ws = (char*)d_ws;
  float* pre_g = (float*)(ws);                              // 8,388,608
  float* pre_c = (float*)(ws + 8388608);                    // 4,194,304
  __hip_bfloat16* A = (__hip_bfloat16*)(ws + 12582912);     // 2,097,152
  __hip_bfloat16* WoutT = (__hip_bfloat16*)(ws + 14680064); // 32,768,000
  uint4* Wg2 = (uint4*)(ws + 47448064);                     // 1,048,576
  uint4* Wc2 = (uint4*)(ws + 48496640);                     //   524,288
  u32t* RH = (u32t*)(ws + 49020928);                        //    32,768
  u32t* HB = (u32t*)(ws + 49053696);                        //    32,768
  int* flags = (int*)(ws + 49086464);                       //   131,072 (flagR | flagH)
  int* flagR = flags;                                       // 32*8 slices, 256B spaced
  int* flagH = flags + 16384;

  hipLaunchKernelGGL(k_pack_g2, dim3(256), dim3(256), 0, stream, Wg, Wg2);
  hipLaunchKernelGGL(k_pack_c2, dim3(128), dim3(256), 0, stream, Wc, Wc2);
  hipLaunchKernelGGL(k_transpose, dim3(500, 8), dim3(256), 0, stream, Wout, WoutT);
  hipLaunchKernelGGL(k_precompute_g, dim3(256, 4), dim3(256), 0, stream,
                     widx, embW, Wg, bg, pre_g);
  hipLaunchKernelGGL(k_precompute_c, dim3(256, 2), dim3(256), 0, stream,
                     widx, embW, Wc, bc, pre_c);
  hipLaunchKernelGGL(k_gru_init, dim3(32), dim3(256), 0, stream, enc, HB, flags);
  hipLaunchKernelGGL(k_gru5, dim3(32 * NSL), dim3(512), 0, stream,
                     num_words, Wg2, Wc2, pre_g, pre_c, RH, HB, flagR, flagH, (u32t*)A);
  hipLaunchKernelGGL(k_proj, dim3(16, 250), dim3(256), 0, stream, A, WoutT, bout, out);
}